// Round 11
// baseline (202.648 us; speedup 1.0000x reference)
//
#include <hip/hip_runtime.h>
#include <hip/hip_bf16.h>

typedef __attribute__((ext_vector_type(8))) short short8;
typedef __attribute__((ext_vector_type(4))) float f32x4;
typedef __attribute__((ext_vector_type(4))) unsigned short ushort4v;
typedef unsigned short u16;
typedef unsigned int u32;

#define MFMA32(a, b, c) __builtin_amdgcn_mfma_f32_16x16x32_bf16((a), (b), (c), 0, 0, 0)

// ws layout (u16 units): W^T [3][64][256] at 0; then per-batch q[t][64], k[s][64], vT[64][256]
#define Q_OFF   49152
#define K_OFF   (49152 + 8388608)
#define VT_OFF  (49152 + 16777216)
#define WS_NEED ((49152 + 25165824) * 2)     // bytes

__device__ __forceinline__ u16 f2bf(float f) {
    union { float f; u32 u; } v; v.f = f;
    u32 r = v.u + 0x7FFFu + ((v.u >> 16) & 1u);   // RNE
    return (u16)(r >> 16);
}
__device__ __forceinline__ u32 pack2(float a, float b) {
    return ((u32)f2bf(b) << 16) | (u32)f2bf(a);
}

// ---- ws W^T: ws[m][n][c] = bf16(Wm[c][n])  (R10-verified) ----
__global__ void prep_w(const float* __restrict__ Wq, const float* __restrict__ Wk,
                       const float* __restrict__ Wv, u16* __restrict__ ws)
{
    const int bid = blockIdx.x;          // 0..47
    const int m   = bid >> 4;
    const int seg = bid & 15;
    const int n   = threadIdx.x & 63;
    const int c   = seg * 16 + (threadIdx.x >> 6);
    const float* W = (m == 0) ? Wq : (m == 1) ? Wk : Wv;
    ws[m * 16384 + n * 256 + c] = f2bf(W[c * 64 + n]);
}

// ---- projection: block = (batch, 64-row quarter); wave w owns 16-row tile ----
// Normal-operand MFMA (R10-verified math), staged in LDS, coalesced bf16 stores.
__global__ __launch_bounds__(256, 6)
void proj_qkv(const float* __restrict__ x, u16* __restrict__ ws)
{
    __shared__ __align__(16) u16 tq[64][72];   // q quarter-tile [t_loc][h]
    __shared__ __align__(16) u16 tk[64][72];   // k quarter-tile [s_loc][h]
    __shared__ __align__(16) u16 tv[64][72];   // v^T slice     [h][s_loc]

    const int bid = blockIdx.x;
    const int b  = bid >> 2, qt = bid & 3;
    const int tid = threadIdx.x;
    const int w  = tid >> 6, l = tid & 63, lr = l & 15, lg = l >> 4;
    const int tl = 16 * w;                 // local row base in quarter
    const int Tb = 64 * qt + tl;           // global row base

    // x A-fragments: A[row=lr][k=32ks+8lg+i]
    short8 af[8];
    {
        const float* xr = x + (size_t)b * 65536 + (size_t)(Tb + lr) * 256 + lg * 8;
        #pragma unroll
        for (int ks = 0; ks < 8; ++ks) {
            f32x4 a0 = *(const f32x4*)(xr + ks * 32);
            f32x4 a1 = *(const f32x4*)(xr + ks * 32 + 4);
            short8 f;
            f[0] = (short)f2bf(a0[0]); f[1] = (short)f2bf(a0[1]);
            f[2] = (short)f2bf(a0[2]); f[3] = (short)f2bf(a0[3]);
            f[4] = (short)f2bf(a1[0]); f[5] = (short)f2bf(a1[1]);
            f[6] = (short)f2bf(a1[2]); f[7] = (short)f2bf(a1[3]);
            af[ks] = f;
        }
    }

    #pragma unroll
    for (int m = 0; m < 3; ++m) {          // 0=q, 1=k, 2=v
        const u16* wsm = ws + m * 16384;
        f32x4 acc[4];
        #pragma unroll
        for (int nj = 0; nj < 4; ++nj) acc[nj] = (f32x4){0.f, 0.f, 0.f, 0.f};
        #pragma unroll
        for (int ks = 0; ks < 8; ++ks)
            #pragma unroll
            for (int nj = 0; nj < 4; ++nj) {
                short8 bf = *(const short8*)&wsm[(16 * nj + lr) * 256 + 32 * ks + 8 * lg];
                acc[nj] = MFMA32(af[ks], bf, acc[nj]);
            }
        // D[t = base+4lg+j][n = 16nj+lr]
        if (m == 0) {
            #pragma unroll
            for (int nj = 0; nj < 4; ++nj)
                #pragma unroll
                for (int j = 0; j < 4; ++j)
                    tq[tl + 4 * lg + j][16 * nj + lr] = f2bf(acc[nj][j]);
        } else if (m == 1) {
            #pragma unroll
            for (int nj = 0; nj < 4; ++nj)
                #pragma unroll
                for (int j = 0; j < 4; ++j)
                    tk[tl + 4 * lg + j][16 * nj + lr] = f2bf(acc[nj][j]);
        } else {
            #pragma unroll
            for (int nj = 0; nj < 4; ++nj) {
                ushort4v pk;
                pk[0] = f2bf(acc[nj][0]); pk[1] = f2bf(acc[nj][1]);
                pk[2] = f2bf(acc[nj][2]); pk[3] = f2bf(acc[nj][3]);
                *(ushort4v*)&tv[16 * nj + lr][tl + 4 * lg] = pk;
            }
        }
    }
    __syncthreads();

    // cooperative coalesced stores: 2 reps x (32 rows x 8 segs of 8 u16)
    u16* qg  = ws + Q_OFF  + (size_t)b * 16384;
    u16* kg  = ws + K_OFF  + (size_t)b * 16384;
    u16* vtg = ws + VT_OFF + (size_t)b * 16384;
    #pragma unroll
    for (int rep = 0; rep < 2; ++rep) {
        const int row = (tid >> 3) + 32 * rep;   // 0..63
        const int sg  = tid & 7;
        *(short8*)&qg[(size_t)(64 * qt + row) * 64 + 8 * sg]  = *(const short8*)&tq[row][8 * sg];
        *(short8*)&kg[(size_t)(64 * qt + row) * 64 + 8 * sg]  = *(const short8*)&tk[row][8 * sg];
        *(short8*)&vtg[(size_t)row * 256 + 64 * qt + 8 * sg]  = *(const short8*)&tv[row][8 * sg];
    }
}

// ---- attention: zero LDS, zero barriers; wave w of block (b,qt) owns t-tile 4qt+w ----
// Swapped QK^T (A=k, B=q row-read), scalar online softmax, bpermute PV (R10-verified).
__global__ __launch_bounds__(256, 6)
void attn(const u16* __restrict__ ws, const float* __restrict__ dmask,
          float* __restrict__ out)
{
    const int bid = blockIdx.x;
    const int b  = bid >> 2, qt = bid & 3;
    const int tid = threadIdx.x;
    const int w  = tid >> 6, l = tid & 63, lr = l & 15, lg = l >> 4;
    const int tl = 4 * qt + w;         // t-tile 0..15
    const int Tb = 16 * tl;
    const int nst = tl + 1;
    const int t_my = Tb + lr;

    const u16* qg  = ws + Q_OFF  + (size_t)b * 16384;
    const u16* kg  = ws + K_OFF  + (size_t)b * 16384;
    const u16* vtg = ws + VT_OFF + (size_t)b * 16384;
    const float* mb = dmask + (size_t)b * 65536;

    // q B-frags: natural row reads, q[t=lr-col][h=slot]
    short8 qf0 = *(const short8*)&qg[(size_t)(Tb + lr) * 64 + 8 * lg];
    short8 qf1 = *(const short8*)&qg[(size_t)(Tb + lr) * 64 + 32 + 8 * lg];

    // bpermute transpose addresses (R10-verified)
    int adr[4];
    #pragma unroll
    for (int e = 0; e < 4; ++e) {
        const int lgp = ((8 * lg + 2 * e) & 15) >> 2;
        adr[e] = 4 * (lr + 16 * lgp);
    }

    float m_ = -1e30f, ls = 0.f;
    f32x4 O[4];
    #pragma unroll
    for (int ht = 0; ht < 4; ++ht) O[ht] = (f32x4){0.f, 0.f, 0.f, 0.f};

    for (int c2 = 0; 2 * c2 < nst; ++c2) {
        // dropout masks early (fly under QK + softmax)
        f32x4 md0 = *(const f32x4*)&mb[(size_t)t_my * 256 + 32 * c2 + 4 * lg];
        f32x4 md1 = *(const f32x4*)&mb[(size_t)t_my * 256 + 32 * c2 + 16 + 4 * lg];

        // QK^T swapped: S[t=lr][s = 32c2 + 16sl + 4lg + j]
        f32x4 S0, S1;
        {
            const u16* kr = &kg[(size_t)(16 * (2 * c2) + lr) * 64];
            short8 kf0 = *(const short8*)&kr[8 * lg];
            short8 kf1 = *(const short8*)&kr[32 + 8 * lg];
            f32x4 a = (f32x4){0.f, 0.f, 0.f, 0.f};
            a = MFMA32(kf0, qf0, a);
            a = MFMA32(kf1, qf1, a);
            S0 = a;
        }
        {
            const u16* kr = &kg[(size_t)(16 * (2 * c2 + 1) + lr) * 64];
            short8 kf0 = *(const short8*)&kr[8 * lg];
            short8 kf1 = *(const short8*)&kr[32 + 8 * lg];
            f32x4 a = (f32x4){0.f, 0.f, 0.f, 0.f};
            a = MFMA32(kf0, qf0, a);
            a = MFMA32(kf1, qf1, a);
            S1 = a;
        }

        // scale + causal + chunk max (scalar per lane)
        float cm = m_;
        #pragma unroll
        for (int j = 0; j < 4; ++j) {
            const int sg0 = 32 * c2 + 4 * lg + j;
            const int sg1 = sg0 + 16;
            float L0 = (sg0 <= t_my) ? S0[j] * 0.125f : -1e30f;
            float L1 = (sg1 <= t_my) ? S1[j] * 0.125f : -1e30f;
            S0[j] = L0; S1[j] = L1;
            cm = fmaxf(cm, fmaxf(L0, L1));
        }
        cm = fmaxf(cm, __shfl_xor(cm, 16, 64));
        cm = fmaxf(cm, __shfl_xor(cm, 32, 64));

        const float fs = exp2f((m_ - cm) * 1.44269504f);   // 0 on first chunk
        m_ = cm;

        float cs = 0.f;
        #pragma unroll
        for (int j = 0; j < 4; ++j) {
            float p0 = exp2f((S0[j] - cm) * 1.44269504f);
            float p1 = exp2f((S1[j] - cm) * 1.44269504f);
            S0[j] = p0; S1[j] = p1;
            cs += p0 + p1;
        }
        cs += __shfl_xor(cs, 16, 64);
        cs += __shfl_xor(cs, 32, 64);
        ls = ls * fs + cs;
        #pragma unroll
        for (int ht = 0; ht < 4; ++ht) O[ht] *= fs;

        // dropout (unnormalized P), pack, lane-transpose to PV B-frag
        #pragma unroll
        for (int j = 0; j < 4; ++j) {
            S0[j] = (md0[j] >= 0.25f) ? S0[j] : 0.f;
            S1[j] = (md1[j] >= 0.25f) ? S1[j] : 0.f;
        }
        u32 pk0[2], pk1[2];
        pk0[0] = pack2(S0[0], S0[1]); pk0[1] = pack2(S0[2], S0[3]);
        pk1[0] = pack2(S1[0], S1[1]); pk1[1] = pack2(S1[2], S1[3]);
        union { u32 u[4]; short8 s; } pf;
        #pragma unroll
        for (int e = 0; e < 4; ++e) {
            u32 ca = (u32)__builtin_amdgcn_ds_bpermute(adr[e], (int)pk0[e & 1]);
            u32 cb = (u32)__builtin_amdgcn_ds_bpermute(adr[e], (int)pk1[e & 1]);
            pf.u[e] = (lg >> 1) ? cb : ca;
        }

        #pragma unroll
        for (int ht = 0; ht < 4; ++ht) {
            short8 vf = *(const short8*)&vtg[(size_t)(16 * ht + lr) * 256 + 32 * c2 + 8 * lg];
            O[ht] = MFMA32(vf, pf.s, O[ht]);
        }
    }

    // normalize + store
    const float rf = 1.33333333333f / ls;    // (1/sum) * 1/(1-0.25)
    float* ob = out + (size_t)b * 16384;
    #pragma unroll
    for (int ht = 0; ht < 4; ++ht) {
        f32x4 o = O[ht] * rf;
        *(f32x4*)&ob[(size_t)t_my * 64 + 16 * ht + 4 * lg] = o;
    }
}

extern "C" void kernel_launch(void* const* d_in, const int* in_sizes, int n_in,
                              void* d_out, int out_size, void* d_ws, size_t ws_size,
                              hipStream_t stream) {
    const float* x  = (const float*)d_in[0];
    const float* Wq = (const float*)d_in[1];
    const float* Wk = (const float*)d_in[2];
    const float* Wv = (const float*)d_in[3];
    const float* dm = (const float*)d_in[4];
    float* outp     = (float*)d_out;
    u16* wsp        = (u16*)d_ws;

    if (ws_size < (size_t)WS_NEED) return;   // fail-visible, no OOB writes

    prep_w  <<<dim3(48),   dim3(1024), 0, stream>>>(Wq, Wk, Wv, wsp);
    proj_qkv<<<dim3(2048), dim3(256),  0, stream>>>(x, wsp);
    attn    <<<dim3(2048), dim3(256),  0, stream>>>(wsp, dm, outp);
}

// Round 12
// 109.064 us; speedup vs baseline: 1.8581x; 1.8581x over previous
//
#include <hip/hip_runtime.h>
#include <hip/hip_bf16.h>

typedef __attribute__((ext_vector_type(8))) short short8;
typedef __attribute__((ext_vector_type(4))) float f32x4;
typedef __attribute__((ext_vector_type(4))) unsigned short ushort4v;
typedef unsigned short u16;

#define MFMA32(a, b, c) __builtin_amdgcn_mfma_f32_16x16x32_bf16((a), (b), (c), 0, 0, 0)

__device__ __forceinline__ u16 f2bf(float f) {
    union { float f; unsigned int u; } v; v.f = f;
    unsigned int r = v.u + 0x7FFFu + ((v.u >> 16) & 1u);   // RNE
    return (u16)(r >> 16);
}

// Rolled flash attention for one 16-row t-tile (R7-verified body, unchanged).
__device__ __forceinline__ void do_tile(int Tb, int nst, int lr, int lg,
                                        const short8* qf,           // [2]
                                        const u16 (*lk)[72],
                                        const u16 (*lvT)[264],
                                        u16* pbw,                   // wave-private [16][40]
                                        const float* mb, float* ob)
{
    const int tb = Tb + 4 * lg;
    float m[4], ls[4];
    f32x4 O[4];
    #pragma unroll
    for (int j = 0; j < 4; ++j) { m[j] = -1e30f; ls[j] = 0.f; }
    #pragma unroll
    for (int ht = 0; ht < 4; ++ht) O[ht] = (f32x4){0.f, 0.f, 0.f, 0.f};

    float pm[2][4];
    #pragma unroll
    for (int sl = 0; sl < 2; ++sl) {
        #pragma unroll
        for (int j = 0; j < 4; ++j) pm[sl][j] = 0.f;
        if (sl < nst) {
            #pragma unroll
            for (int j = 0; j < 4; ++j)
                pm[sl][j] = mb[(size_t)(tb + j) * 256 + 16 * sl + lr];
        }
    }

    #pragma unroll 1
    for (int c = 0; 2 * c < nst; ++c) {
        float nm[2][4];
        #pragma unroll
        for (int sl = 0; sl < 2; ++sl) {
            const int stn = 2 * c + 2 + sl;
            #pragma unroll
            for (int j = 0; j < 4; ++j) nm[sl][j] = 0.f;
            if (stn < nst) {
                #pragma unroll
                for (int j = 0; j < 4; ++j)
                    nm[sl][j] = mb[(size_t)(tb + j) * 256 + 16 * stn + lr];
            }
        }

        f32x4 S[2];
        #pragma unroll
        for (int sl = 0; sl < 2; ++sl) {
            const u16* kr = &lk[16 * (2 * c + sl) + lr][0];
            ushort4v t0 = *(const ushort4v*)&kr[4 * lg];
            ushort4v t1 = *(const ushort4v*)&kr[16 + 4 * lg];
            ushort4v t2 = *(const ushort4v*)&kr[32 + 4 * lg];
            ushort4v t3 = *(const ushort4v*)&kr[48 + 4 * lg];
            short8 kf0, kf1;
            kf0[0]=(short)t0[0]; kf0[1]=(short)t0[1]; kf0[2]=(short)t0[2]; kf0[3]=(short)t0[3];
            kf0[4]=(short)t1[0]; kf0[5]=(short)t1[1]; kf0[6]=(short)t1[2]; kf0[7]=(short)t1[3];
            kf1[0]=(short)t2[0]; kf1[1]=(short)t2[1]; kf1[2]=(short)t2[2]; kf1[3]=(short)t2[3];
            kf1[4]=(short)t3[0]; kf1[5]=(short)t3[1]; kf1[6]=(short)t3[2]; kf1[7]=(short)t3[3];
            f32x4 a = (f32x4){0.f, 0.f, 0.f, 0.f};
            a = MFMA32(qf[0], kf0, a);
            a = MFMA32(qf[1], kf1, a);
            S[sl] = a;
        }

        float cm[4];
        #pragma unroll
        for (int j = 0; j < 4; ++j) cm[j] = m[j];
        #pragma unroll
        for (int sl = 0; sl < 2; ++sl) {
            const int s = 16 * (2 * c + sl) + lr;
            #pragma unroll
            for (int j = 0; j < 4; ++j) {
                float Lv = (s <= tb + j) ? S[sl][j] * 0.125f : -1e30f;
                S[sl][j] = Lv;
                cm[j] = fmaxf(cm[j], Lv);
            }
        }
        #pragma unroll
        for (int d = 1; d < 16; d <<= 1)
            #pragma unroll
            for (int j = 0; j < 4; ++j)
                cm[j] = fmaxf(cm[j], __shfl_xor(cm[j], d, 64));

        float fs[4];
        #pragma unroll
        for (int j = 0; j < 4; ++j)
            fs[j] = exp2f((m[j] - cm[j]) * 1.44269504f);
        {
            float fsel = (lr & 3) == 0 ? fs[0] : (lr & 3) == 1 ? fs[1]
                       : (lr & 3) == 2 ? fs[2] : fs[3];
            float fO = __shfl(fsel, ((lr >> 2) << 4) | lr, 64);
            #pragma unroll
            for (int ht = 0; ht < 4; ++ht) O[ht] *= fO;
        }
        #pragma unroll
        for (int j = 0; j < 4; ++j) m[j] = cm[j];

        float cs[4] = {0.f, 0.f, 0.f, 0.f};
        #pragma unroll
        for (int sl = 0; sl < 2; ++sl)
            #pragma unroll
            for (int j = 0; j < 4; ++j) {
                float p = exp2f((S[sl][j] - m[j]) * 1.44269504f);
                S[sl][j] = p;
                cs[j] += p;
            }
        #pragma unroll
        for (int d = 1; d < 16; d <<= 1)
            #pragma unroll
            for (int j = 0; j < 4; ++j)
                cs[j] += __shfl_xor(cs[j], d, 64);
        #pragma unroll
        for (int j = 0; j < 4; ++j)
            ls[j] = ls[j] * fs[j] + cs[j];

        #pragma unroll
        for (int sl = 0; sl < 2; ++sl)
            #pragma unroll
            for (int j = 0; j < 4; ++j) {
                float p = (pm[sl][j] >= 0.25f) ? S[sl][j] : 0.f;
                pbw[(4 * lg + j) * 40 + 16 * sl + lr] = f2bf(p);
            }
        asm volatile("s_waitcnt lgkmcnt(0)" ::: "memory");
        __builtin_amdgcn_sched_barrier(0);
        short8 pf = *(const short8*)&pbw[lr * 40 + 8 * lg];
        #pragma unroll
        for (int ht = 0; ht < 4; ++ht) {
            short8 vf = *(const short8*)&lvT[16 * ht + lr][32 * c + 8 * lg];
            O[ht] = MFMA32(vf, pf, O[ht]);
        }
        #pragma unroll
        for (int sl = 0; sl < 2; ++sl)
            #pragma unroll
            for (int j = 0; j < 4; ++j)
                pm[sl][j] = nm[sl][j];
    }

    float rs[4];
    #pragma unroll
    for (int j = 0; j < 4; ++j)
        rs[j] = 1.33333333333f / ls[j];     // (1/sum) * 1/(1-0.25)
    float rsel = (lr & 3) == 0 ? rs[0] : (lr & 3) == 1 ? rs[1]
               : (lr & 3) == 2 ? rs[2] : rs[3];
    float rfin = __shfl(rsel, ((lr >> 2) << 4) | lr, 64);
    #pragma unroll
    for (int ht = 0; ht < 4; ++ht) {
        f32x4 o = O[ht] * rfin;
        *(f32x4*)&ob[(size_t)(Tb + lr) * 64 + 16 * ht + 4 * lg] = o;
    }
}

// stage full W^T bf16 into wt: lane l owns row n=l; wave w owns chunks 8(w+8i)
#define STAGE_W(Wm) do {                                                     \
    _Pragma("unroll")                                                        \
    for (int i_ = 0; i_ < 4; ++i_) {                                         \
        const int c0_ = 8 * (w + 8 * i_);                                    \
        short8 t_;                                                           \
        _Pragma("unroll")                                                    \
        for (int j_ = 0; j_ < 8; ++j_)                                       \
            t_[j_] = (short)f2bf((Wm)[(size_t)(c0_ + j_) * 64 + l]);         \
        *(short8*)&wt[l][c0_] = t_;                                          \
    } } while (0)

// issue one tile's x rows into f32 registers (16 x f32x4, stay in flight)
#define ISSUE_X(dst, xb_, Tbase) do {                                        \
    const float* xr_ = (xb_) + (size_t)((Tbase) + lr) * 256 + lg * 8;        \
    _Pragma("unroll")                                                        \
    for (int ks_ = 0; ks_ < 8; ++ks_) {                                      \
        dst[2 * ks_]     = *(const f32x4*)(xr_ + ks_ * 32);                  \
        dst[2 * ks_ + 1] = *(const f32x4*)(xr_ + ks_ * 32 + 4);              \
    } } while (0)

// convert a prefetched tile to bf16 A-fragments
#define CVT_X(af_, src) do {                                                 \
    _Pragma("unroll")                                                        \
    for (int ks_ = 0; ks_ < 8; ++ks_) {                                      \
        f32x4 a0_ = src[2 * ks_], a1_ = src[2 * ks_ + 1];                    \
        short8 f_;                                                           \
        f_[0] = (short)f2bf(a0_[0]); f_[1] = (short)f2bf(a0_[1]);            \
        f_[2] = (short)f2bf(a0_[2]); f_[3] = (short)f2bf(a0_[3]);            \
        f_[4] = (short)f2bf(a1_[0]); f_[5] = (short)f2bf(a1_[1]);            \
        f_[6] = (short)f2bf(a1_[2]); f_[7] = (short)f2bf(a1_[3]);            \
        (af_)[ks_] = f_;                                                     \
    } } while (0)

// full projection phase for the current batch: af[2][8] -> lk, lvT, qf
#define DO_PROJ(qf_) do {                                                    \
    f32x4 acc[2][4];                                                         \
    /* k */                                                                  \
    STAGE_W(Wk);                                                             \
    __syncthreads();                                                         \
    _Pragma("unroll")                                                        \
    for (int ti = 0; ti < 2; ++ti)                                           \
        _Pragma("unroll")                                                    \
        for (int nj = 0; nj < 4; ++nj) acc[ti][nj] = (f32x4){0.f,0.f,0.f,0.f}; \
    _Pragma("unroll")                                                        \
    for (int ks = 0; ks < 8; ++ks)                                           \
        _Pragma("unroll")                                                    \
        for (int nj = 0; nj < 4; ++nj) {                                     \
            short8 bf = *(const short8*)&wt[16 * nj + lr][ks * 32 + lg * 8]; \
            acc[0][nj] = MFMA32(af[0][ks], bf, acc[0][nj]);                  \
            acc[1][nj] = MFMA32(af[1][ks], bf, acc[1][nj]);                  \
        }                                                                    \
    _Pragma("unroll")                                                        \
    for (int nj = 0; nj < 4; ++nj) {                                         \
        const int n = 16 * nj + lr;                                          \
        _Pragma("unroll")                                                    \
        for (int j = 0; j < 4; ++j) {                                        \
            lk[TbA + 4 * lg + j][n] = f2bf(acc[0][nj][j]);                   \
            lk[TbB + 4 * lg + j][n] = f2bf(acc[1][nj][j]);                   \
        }                                                                    \
    }                                                                        \
    __syncthreads();                                                         \
    /* v */                                                                  \
    STAGE_W(Wv);                                                             \
    __syncthreads();                                                         \
    _Pragma("unroll")                                                        \
    for (int ti = 0; ti < 2; ++ti)                                           \
        _Pragma("unroll")                                                    \
        for (int nj = 0; nj < 4; ++nj) acc[ti][nj] = (f32x4){0.f,0.f,0.f,0.f}; \
    _Pragma("unroll")                                                        \
    for (int ks = 0; ks < 8; ++ks)                                           \
        _Pragma("unroll")                                                    \
        for (int nj = 0; nj < 4; ++nj) {                                     \
            short8 bf = *(const short8*)&wt[16 * nj + lr][ks * 32 + lg * 8]; \
            acc[0][nj] = MFMA32(af[0][ks], bf, acc[0][nj]);                  \
            acc[1][nj] = MFMA32(af[1][ks], bf, acc[1][nj]);                  \
        }                                                                    \
    _Pragma("unroll")                                                        \
    for (int ti = 0; ti < 2; ++ti) {                                         \
        const int s0 = (ti ? TbB : TbA) + 4 * lg;                            \
        _Pragma("unroll")                                                    \
        for (int nj = 0; nj < 4; ++nj) {                                     \
            ushort4v pk;                                                     \
            pk[0] = f2bf(acc[ti][nj][0]);                                    \
            pk[1] = f2bf(acc[ti][nj][1]);                                    \
            pk[2] = f2bf(acc[ti][nj][2]);                                    \
            pk[3] = f2bf(acc[ti][nj][3]);                                    \
            *(ushort4v*)&lvT[16 * nj + lr][s0] = pk;                         \
        }                                                                    \
    }                                                                        \
    __syncthreads();                                                         \
    /* q (SWAPPED operands -> q^T frags) */                                  \
    STAGE_W(Wq);                                                             \
    __syncthreads();                                                         \
    _Pragma("unroll")                                                        \
    for (int ti = 0; ti < 2; ++ti)                                           \
        _Pragma("unroll")                                                    \
        for (int nj = 0; nj < 4; ++nj) acc[ti][nj] = (f32x4){0.f,0.f,0.f,0.f}; \
    _Pragma("unroll")                                                        \
    for (int ks = 0; ks < 8; ++ks)                                           \
        _Pragma("unroll")                                                    \
        for (int nj = 0; nj < 4; ++nj) {                                     \
            short8 bf = *(const short8*)&wt[16 * nj + lr][ks * 32 + lg * 8]; \
            acc[0][nj] = MFMA32(bf, af[0][ks], acc[0][nj]);                  \
            acc[1][nj] = MFMA32(bf, af[1][ks], acc[1][nj]);                  \
        }                                                                    \
    _Pragma("unroll")                                                        \
    for (int nj = 0; nj < 4; ++nj)                                           \
        _Pragma("unroll")                                                    \
        for (int j = 0; j < 4; ++j) {                                        \
            qf_[0][nj >> 1][(nj & 1) * 4 + j] = (short)f2bf(acc[0][nj][j]);  \
            qf_[1][nj >> 1][(nj & 1) * 4 + j] = (short)f2bf(acc[1][nj][j]);  \
        }                                                                    \
    } while (0)

// Grid = 256: each block processes batches b and b+256 back-to-back.
// Batch b+256's x-fragment loads are ISSUED before batch b's attention and
// stay in flight (128 f32 regs) until converted at batch b+256's start —
// hiding the second x-load HBM burst under compute. LDS = 114688 -> 1 blk/CU.
__global__ __launch_bounds__(512, 2)
void attn_head_fused(const float* __restrict__ x,
                     const float* __restrict__ Wq,
                     const float* __restrict__ Wk,
                     const float* __restrict__ Wv,
                     const float* __restrict__ dmask,
                     float* __restrict__ out)
{
    __shared__ __align__(16) u16 lk[256][72];       // k [s][h]    36864 B
    __shared__ __align__(16) u16 lvT[64][264];      // v^T [h][s]  33792 B
    __shared__ __align__(16) u16 wt[64][264];       // W^T [n][c]  33792 B
    __shared__ __align__(16) u16 pb[8][16][40];     // per-wave P^T 10240 B

    const int b0  = blockIdx.x;
    const int b1  = blockIdx.x + 256;
    const int tid = threadIdx.x;
    const int w   = tid >> 6;
    const int l   = tid & 63;
    const int lr  = l & 15;
    const int lg  = l >> 4;

    const int TbA  = 16 * w;
    const int TbB  = 16 * (15 - w);
    const int nst0 = w + 1;
    const int nst1 = 16 - w;

    const float* xb0 = x + (size_t)b0 * 65536;
    const float* xb1 = x + (size_t)b1 * 65536;

    // ---- prefetch batch-0 x (both tiles) ----
    f32x4 xpA[16], xpB[16];
    ISSUE_X(xpA, xb0, TbA);
    ISSUE_X(xpB, xb0, TbB);

    short8 af[2][8];
    short8 qf[2][2];

    // ================= batch 0 =================
    CVT_X(af[0], xpA);
    CVT_X(af[1], xpB);

    DO_PROJ(qf);

    // issue batch-1 x loads NOW — they stream during batch-0's attention
    ISSUE_X(xpA, xb1, TbA);
    ISSUE_X(xpB, xb1, TbB);

    {
        const float* mb = dmask + (size_t)b0 * 65536;
        float* ob = out + (size_t)b0 * 16384;
        u16* pbw = &pb[w][0][0];
        do_tile(TbA, nst0, lr, lg, qf[0], lk, lvT, pbw, mb, ob);
        do_tile(TbB, nst1, lr, lg, qf[1], lk, lvT, pbw, mb, ob);
    }

    __syncthreads();   // batch-0 LDS reads done before overwrite

    // ================= batch 1 =================
    CVT_X(af[0], xpA);
    CVT_X(af[1], xpB);

    DO_PROJ(qf);

    {
        const float* mb = dmask + (size_t)b1 * 65536;
        float* ob = out + (size_t)b1 * 16384;
        u16* pbw = &pb[w][0][0];
        do_tile(TbA, nst0, lr, lg, qf[0], lk, lvT, pbw, mb, ob);
        do_tile(TbB, nst1, lr, lg, qf[1], lk, lvT, pbw, mb, ob);
    }
}

extern "C" void kernel_launch(void* const* d_in, const int* in_sizes, int n_in,
                              void* d_out, int out_size, void* d_ws, size_t ws_size,
                              hipStream_t stream) {
    const float* x  = (const float*)d_in[0];
    const float* Wq = (const float*)d_in[1];
    const float* Wk = (const float*)d_in[2];
    const float* Wv = (const float*)d_in[3];
    const float* dm = (const float*)d_in[4];
    float* outp     = (float*)d_out;
    attn_head_fused<<<dim3(256), dim3(512), 0, stream>>>(x, Wq, Wk, Wv, dm, outp);
}